// Round 6
// baseline (321.551 us; speedup 1.0000x reference)
//
#include <hip/hip_runtime.h>
#include <hip/hip_bf16.h>

#define DEV __device__ __forceinline__

typedef __bf16 bf16x8 __attribute__((ext_vector_type(8)));
typedef __bf16 bf16x4 __attribute__((ext_vector_type(4)));
typedef float f32x4 __attribute__((ext_vector_type(4)));

static constexpr int kB = 2, kT = 2048, kD = 2048, kH = 16, kHD = 128;
static constexpr int kBT = kB * kT;  // 4096

// fast 2^x: v_exp_f32 computes exp2 natively on gfx950
#if __has_builtin(__builtin_amdgcn_exp2f)
DEV float fast_exp2(float x) { return __builtin_amdgcn_exp2f(x); }
#else
DEV float fast_exp2(float x) { return exp2f(x); }
#endif

DEV unsigned short f2bf(float f) {
  union { __hip_bfloat16 h; unsigned short u; } cv;
  cv.h = __float2bfloat16(f);
  return cv.u;
}

// async global->LDS, 16B per lane. LDS dest must be wave-uniform base + lane*16.
DEV void gl_lds16(const void* g, void* l) {
  __builtin_amdgcn_global_load_lds(
      (const __attribute__((address_space(1))) unsigned int*)g,
      (__attribute__((address_space(3))) unsigned int*)l, 16, 0, 0);
}

#define MFMA(a, b, c) __builtin_amdgcn_mfma_f32_16x16x32_bf16(a, b, c, 0, 0, 0)

// bank swizzle for [rows]x32 bf16 tiles staged via global_load_lds:
// slot = row*4 + (chunk ^ swz(row)); swz covers row bits 0..3 so frag-read
// lanes {i,i+4,i+8,i+12} land in distinct 16B chunks -> 2-way max (free).
DEV int swz4(int row) { return (row ^ (row >> 2)) & 3; }

// ---------------- fused prep: make_vt + x->bf16 + 3 weight converts ---------
// blocks [0,1024): make_vt for (t0,h,b); ALSO emits xb for its x-patch
//   (x is loaded here anyway -> saves the 64MB fp32 re-read cvt4 did).
// blocks [1024,13312): fp32->bf16 convert of Wq/Wk/Wo (4096 blocks each).
__global__ __launch_bounds__(256) void prep_kernel(
    const float* __restrict__ x, const float* __restrict__ v_embed,
    const float* __restrict__ Wq, const float* __restrict__ Wk,
    const float* __restrict__ Wo, unsigned short* __restrict__ vt,
    unsigned short* __restrict__ xb, unsigned short* __restrict__ wqb,
    unsigned short* __restrict__ wkb, unsigned short* __restrict__ wob) {
  const int tid = threadIdx.x;
  const int bx = blockIdx.x;
  if (bx >= 1024) {
    // ---- weight convert: 3 x (kD*kD/4 float4), 4096 blocks each ----
    const int j = bx - 1024;
    const int which = j >> 12;             // 0..2
    const int i = (j & 4095) * 256 + tid;  // < kD*kD/4 exactly
    const float* s = which == 0 ? Wq : which == 1 ? Wk : Wo;
    unsigned short* d = which == 0 ? wqb : which == 1 ? wkb : wob;
    float4 v = ((const float4*)s)[i];
    ushort4 o;
    o.x = f2bf(v.x); o.y = f2bf(v.y); o.z = f2bf(v.z); o.w = f2bf(v.w);
    ((ushort4*)d)[i] = o;
    return;
  }
  // ---- make_vt: V^T = (x * c) transposed to [b][h][hd][T], bf16 ----
  // top_k with TOPK==NVK==4 selects ALL rows -> c[d] = 2*sum_{k<4} v_embed[k][d].
  __shared__ __align__(16) unsigned short sT[128 * 72];  // [hd][t], stride 72
  const int t0 = (bx & 31) * 64, h = (bx >> 5) & 15, b = bx >> 9;
  const int d4 = tid & 31, r8 = tid >> 5;
  const int dg = h * kHD + d4 * 4;
  float4 e0 = *(const float4*)(v_embed + dg);
  float4 e1 = *(const float4*)(v_embed + kD + dg);
  float4 e2 = *(const float4*)(v_embed + 2 * kD + dg);
  float4 e3 = *(const float4*)(v_embed + 3 * kD + dg);
  float4 c4;
  c4.x = 2.f * (e0.x + e1.x + e2.x + e3.x);
  c4.y = 2.f * (e0.y + e1.y + e2.y + e3.y);
  c4.z = 2.f * (e0.z + e1.z + e2.z + e3.z);
  c4.w = 2.f * (e0.w + e1.w + e2.w + e3.w);
#pragma unroll
  for (int it = 0; it < 8; it++) {
    const int t = r8 + it * 8;  // 0..63
    const size_t row = (size_t)(b * kT + t0 + t) * kD + dg;
    float4 v = *(const float4*)(x + row);
    // x -> bf16 (was a separate full read of x in cvt4)
    ushort4 xo;
    xo.x = f2bf(v.x); xo.y = f2bf(v.y); xo.z = f2bf(v.z); xo.w = f2bf(v.w);
    *(ushort4*)(xb + row) = xo;
    sT[(d4 * 4 + 0) * 72 + t] = f2bf(v.x * c4.x);
    sT[(d4 * 4 + 1) * 72 + t] = f2bf(v.y * c4.y);
    sT[(d4 * 4 + 2) * 72 + t] = f2bf(v.z * c4.z);
    sT[(d4 * 4 + 3) * 72 + t] = f2bf(v.w * c4.w);
  }
  __syncthreads();
#pragma unroll
  for (int it = 0; it < 4; it++) {
    const int hd = (tid >> 3) + it * 32;
    const int tt = (tid & 7) * 8;
    bf16x8 vv = *(const bf16x8*)(sT + hd * 72 + tt);
    *(bf16x8*)(vt + ((size_t)((b * kH + h) * kHD + hd)) * kT + t0 + tt) = vv;
  }
}

// ---------------- C[m,n] = (sum_k A[m,k]*B[n,k] + bias[n]) * scale ----------
// 128 x (NREP*32) tile, BK=64 (two independent 128x32 sub-tiles, verified swz4
// layout per sub-tile), 4 waves (2x2), 16x16x32 bf16 MFMA, global_load_lds
// w=16. 2 barriers per NREP*8 MFMA. Inter-block overlap covers the barrier
// drain (m114) — needs 4 blocks/CU, hence NREP=2 (BN=64) for the 512-tile
// out-projection so its grid reaches 1024 blocks.
// T1 XCD swizzle (round-5: FETCH 133->64MB, -5 us): HW XCD = linear_blk % 8;
// remap so each XCD owns a compact tile region (bijective per grid shape).
template <int NREP, bool BF16OUT, bool FUSED2>
__global__ __launch_bounds__(256, 4) void gemm_bt(
    const unsigned short* __restrict__ A, const unsigned short* __restrict__ B1,
    const unsigned short* __restrict__ B2, const float* __restrict__ bias1,
    const float* __restrict__ bias2, void* __restrict__ C1, void* __restrict__ C2,
    float scale1, float scale2) {
  constexpr int BN = NREP * 32;
  constexpr int N = kD, K = kD;
  __shared__ __align__(16) unsigned short As[2][128 * 32], Bs[2][BN * 32];
  int bxn, byn, bzn;
  if constexpr (FUSED2) {
    // grid (16,32,2) = 1024 blocks; per-XCD region: z fixed, 8 n-tiles, 16 m.
    const int lb = blockIdx.x + (blockIdx.y << 4) + (blockIdx.z << 9);
    const int xcd = lb & 7, r = lb >> 3;  // r in [0,128)
    bzn = xcd & 1;
    bxn = (((xcd >> 1) & 1) << 3) + (r & 7);  // n-tile 0..15
    byn = ((xcd >> 2) << 4) + (r >> 3);       // m-tile 0..31
  } else if constexpr (NREP == 2) {
    // grid (32,32,1) = 1024 blocks; per-XCD region: 8 n-tiles x 16 m-tiles.
    const int lb = blockIdx.x + (blockIdx.y << 5);
    const int xcd = lb & 7, r = lb >> 3;  // r in [0,128)
    bzn = 0;
    bxn = ((xcd & 3) << 3) + (r & 7);    // n-tile 0..31
    byn = ((xcd >> 2) << 4) + (r >> 3);  // m-tile 0..31
  } else {
    // grid (16,32,1) = 512 blocks; per-XCD region: 8 n-tiles x 8 m-tiles.
    const int lb = blockIdx.x + (blockIdx.y << 4);
    const int xcd = lb & 7, r = lb >> 3;  // r in [0,64)
    bzn = 0;
    bxn = ((xcd & 1) << 3) + (r & 7);
    byn = ((xcd >> 1) << 3) + (r >> 3);
  }
  const unsigned short* Bm = (FUSED2 && bzn) ? B2 : B1;
  const float* bias = (FUSED2 && bzn) ? bias2 : bias1;
  void* Cout = (FUSED2 && bzn) ? C2 : C1;
  const float scale = (FUSED2 && bzn) ? scale2 : scale1;
  const int tid = threadIdx.x;
  const int lane = tid & 63, wave = tid >> 6;
  const int wr = wave >> 1, wc = wave & 1;
  const int m0 = byn * 128, n0 = bxn * BN;
  const int frow = lane & 15, fc = lane >> 4;

  f32x4 acc[4][NREP];
#pragma unroll
  for (int i = 0; i < 4; i++)
#pragma unroll
    for (int j = 0; j < NREP; j++)
#pragma unroll
      for (int r = 0; r < 4; r++) acc[i][j][r] = 0.f;

  const int r0 = tid >> 2, c0 = (tid & 3) ^ swz4(r0);
  const int p1 = tid + 256;
  const int r1 = p1 >> 2, c1 = (p1 & 3) ^ swz4(r1);

  const unsigned short* Ab = A + (size_t)m0 * K;
  const unsigned short* Bb = Bm + (size_t)n0 * K;

  for (int k0 = 0; k0 < K; k0 += 64) {
    __syncthreads();
#pragma unroll
    for (int hh = 0; hh < 2; hh++) {
      const int kk = k0 + hh * 32;
      gl_lds16(Ab + (size_t)r0 * K + kk + c0 * 8, &As[hh][tid * 8]);
      gl_lds16(Ab + (size_t)r1 * K + kk + c1 * 8, &As[hh][p1 * 8]);
      gl_lds16(Bb + (size_t)r0 * K + kk + c0 * 8, &Bs[hh][tid * 8]);
      if constexpr (NREP == 4)
        gl_lds16(Bb + (size_t)r1 * K + kk + c1 * 8, &Bs[hh][p1 * 8]);
    }
    __syncthreads();
#pragma unroll
    for (int hh = 0; hh < 2; hh++) {
      bf16x8 af[4], bfr[NREP];
#pragma unroll
      for (int mi = 0; mi < 4; mi++) {
        int row = wr * 64 + mi * 16 + frow;
        af[mi] = *(const bf16x8*)(&As[hh][(row * 4 + (fc ^ swz4(row))) * 8]);
      }
#pragma unroll
      for (int ni = 0; ni < NREP; ni++) {
        int row = wc * (NREP * 16) + ni * 16 + frow;
        bfr[ni] = *(const bf16x8*)(&Bs[hh][(row * 4 + (fc ^ swz4(row))) * 8]);
      }
#pragma unroll
      for (int mi = 0; mi < 4; mi++)
#pragma unroll
        for (int ni = 0; ni < NREP; ni++)
          acc[mi][ni] = MFMA(af[mi], bfr[ni], acc[mi][ni]);
    }
  }
  // epilogue: C/D layout col=lane&15, row=(lane>>4)*4+reg
#pragma unroll
  for (int ni = 0; ni < NREP; ni++) {
    const int n = n0 + wc * (NREP * 16) + ni * 16 + frow;
    const float bs = bias[n];
#pragma unroll
    for (int mi = 0; mi < 4; mi++) {
      const int mb = m0 + wr * 64 + mi * 16 + fc * 4;
#pragma unroll
      for (int r = 0; r < 4; r++) {
        const float v = (acc[mi][ni][r] + bs) * scale;
        if (BF16OUT)
          ((unsigned short*)Cout)[(size_t)(mb + r) * N + n] = f2bf(v);
        else
          ((float*)Cout)[(size_t)(mb + r) * N + n] = v;
      }
    }
  }
}

// ---------------- flash attention v2, causal, S^T formulation ----------------
// Q is PRE-SCALED by (1/sqrt(HD))*log2(e); softmax in exp2 domain.
// 1-D grid 512, XCD-swizzled: all 16 pi-blocks of one (b,h) land on one XCD
// (bid&7 = XCD round-robin) so K/V (1MB) is fetched into that L2 once.
// Each block: paired q-tiles (31-pi, pi) -> uniform 33 k-tile units.
// NOTE: round-3 A/B — setprio and defer-max here were net-negative (lockstep
// 4-wave structure = m190 regime); keep the plain round-2 form.
__global__ __launch_bounds__(256, 2) void attn2_kernel(
    const unsigned short* __restrict__ Q, const unsigned short* __restrict__ Kg,
    const unsigned short* __restrict__ Vt, unsigned short* __restrict__ O) {
  __shared__ __align__(16) unsigned short sK[2][64 * 128];  // [key][hd], swizzled
  __shared__ __align__(16) unsigned short sV[2][64 * 128];  // [hd][key], swizzled
  const int tid = threadIdx.x, l = tid & 63, w = tid >> 6;
  const int g = l >> 4, q15 = l & 15;
  const int bid = blockIdx.x;
  const int xcd = bid & 7, rest = bid >> 3;
  const int gidx = xcd + 8 * (rest & 3);  // (b,h) group 0..31
  const int pi = rest >> 2;               // 0..15
  const int h = gidx & 15, b = gidx >> 4;

  for (int half = 0; half < 2; half++) {
    const int qt = half == 0 ? (31 - pi) : pi;
    const int q0 = qt * 64;
    const int nkb = qt + 1;
    const int q = q0 + w * 16 + q15;  // this lane's q column

    __syncthreads();  // buffer reuse safety across halves
    // stage tile 0 -> buf 0
    for (int i = 0; i < 4; i++) {
      const int idx = tid + i * 256;
      const int key = idx >> 4, cc = (idx & 15) ^ (key & 15);
      gl_lds16(Kg + (size_t)(b * kT + key) * kD + h * kHD + cc * 8,
               &sK[0][idx * 8]);
    }
    for (int i = 0; i < 4; i++) {
      const int idx = tid + i * 256;
      const int hd = idx >> 3;
      const int cc = (idx & 7) ^ (hd & 7) ^ (((hd >> 3) & 1) << 2);
      gl_lds16(Vt + ((size_t)((b * kH + h) * kHD + hd)) * kT + cc * 8,
               &sV[0][idx * 8]);
    }

    // Q B-frags (lane holds Q[q][hd = kk*32 + g*8 .. +7])
    bf16x8 qf[4];
    const unsigned short* Qrow = Q + (size_t)(b * kT + q) * kD + h * kHD;
#pragma unroll
    for (int kk = 0; kk < 4; kk++)
      qf[kk] = *(const bf16x8*)(Qrow + kk * 32 + g * 8);

    f32x4 oacc[8];
#pragma unroll
    for (int ni = 0; ni < 8; ni++)
      for (int r = 0; r < 4; r++) oacc[ni][r] = 0.f;
    float m_i = -1e30f, l_i = 0.f;

    for (int kb = 0; kb < nkb; kb++) {
      const int bb = kb & 1;
      __syncthreads();  // drains prefetch(kb) [compiler vmcnt], syncs buffers
      if (kb + 1 < nkb) {
        const int k0n = (kb + 1) * 64;
        const int nb = 1 - bb;
#pragma unroll
        for (int i = 0; i < 4; i++) {
          const int idx = tid + i * 256;
          const int key = idx >> 4, cc = (idx & 15) ^ (key & 15);
          gl_lds16(Kg + (size_t)(b * kT + k0n + key) * kD + h * kHD + cc * 8,
                   &sK[nb][idx * 8]);
        }
#pragma unroll
        for (int i = 0; i < 4; i++) {
          const int idx = tid + i * 256;
          const int hd = idx >> 3;
          const int cc = (idx & 7) ^ (hd & 7) ^ (((hd >> 3) & 1) << 2);
          gl_lds16(Vt + ((size_t)((b * kH + h) * kHD + hd)) * kT + k0n + cc * 8,
                   &sV[nb][idx * 8]);
        }
      }

      // S^T = K Q^T : lane holds S^T[key = s*16 + g*4 + r][q]
      f32x4 st[4];
#pragma unroll
      for (int s = 0; s < 4; s++)
        for (int r = 0; r < 4; r++) st[s][r] = 0.f;
#pragma unroll
      for (int s = 0; s < 4; s++) {
        const int key = s * 16 + q15;  // A-frag row for this lane
#pragma unroll
        for (int kk = 0; kk < 4; kk++) {
          bf16x8 kf = *(const bf16x8*)(
              &sK[bb][(key * 16 + ((kk * 4 + g) ^ (key & 15))) * 8]);
          st[s] = MFMA(kf, qf[kk], st[s]);
        }
      }
      // causal mask (diagonal tile only)
      if (kb == nkb - 1) {
        const int k0 = kb * 64;
#pragma unroll
        for (int s = 0; s < 4; s++)
          for (int r = 0; r < 4; r++)
            if (k0 + s * 16 + g * 4 + r > q) st[s][r] = -1e30f;
      }
      // online softmax (exp2 domain; Q pre-scaled). Per-lane row stats.
      float mx = -1e30f;
#pragma unroll
      for (int s = 0; s < 4; s++)
        for (int r = 0; r < 4; r++) mx = fmaxf(mx, st[s][r]);
      mx = fmaxf(mx, __shfl_xor(mx, 16, 64));
      mx = fmaxf(mx, __shfl_xor(mx, 32, 64));
      const float mn = fmaxf(m_i, mx);
      const float alpha = fast_exp2(m_i - mn);
      float rs = 0.f;
      union { bf16x8 v; unsigned short u[8]; } pkv[2];
#pragma unroll
      for (int s = 0; s < 4; s++)
        for (int r = 0; r < 4; r++) {
          const float p = fast_exp2(st[s][r] - mn);
          rs += p;
          pkv[s >> 1].u[(s & 1) * 4 + r] = f2bf(p);  // slot j=(s&1)*4+r
        }
      rs += __shfl_xor(rs, 16, 64);
      rs += __shfl_xor(rs, 32, 64);
      m_i = mn;
      l_i = l_i * alpha + rs;
#pragma unroll
      for (int ni = 0; ni < 8; ni++)
        for (int r = 0; r < 4; r++) oacc[ni][r] *= alpha;
      // O^T += V^T P^T with K=32 MFMA; A-frag slot (g,j) = key 32c+(j>>2)*16+4g+(j&3)
#pragma unroll
      for (int ni = 0; ni < 8; ni++) {
        const int hd = ni * 16 + q15;
        const int hx = (hd & 7) ^ (((hd >> 3) & 1) << 2), base = hd * 8;
#pragma unroll
        for (int c = 0; c < 2; c++) {
          const int c4l = 8 * c + g;       // keys 32c+4g+0..3   (j=0..3)
          const int c4h = 8 * c + 4 + g;   // keys 32c+16+4g+0..3 (j=4..7)
          bf16x4 lo = *(const bf16x4*)(
              &sV[bb][(base + ((c4l >> 1) ^ hx)) * 8 + (c4l & 1) * 4]);
          bf16x4 hi = *(const bf16x4*)(
              &sV[bb][(base + ((c4h >> 1) ^ hx)) * 8 + (c4h & 1) * 4]);
          bf16x8 vf = __builtin_shufflevector(lo, hi, 0, 1, 2, 3, 4, 5, 6, 7);
          oacc[ni] = MFMA(vf, pkv[c].v, oacc[ni]);
        }
      }
    }
    // epilogue: O^T C-layout -> O[b][t=q][h*128 + hd], 4 contiguous d per lane
    const float inv = 1.f / l_i;
    unsigned short* Orow = O + (size_t)(b * kT + q) * kD + h * kHD;
#pragma unroll
    for (int ni = 0; ni < 8; ni++) {
      ushort4 o4;
      o4.x = f2bf(oacc[ni][0] * inv);
      o4.y = f2bf(oacc[ni][1] * inv);
      o4.z = f2bf(oacc[ni][2] * inv);
      o4.w = f2bf(oacc[ni][3] * inv);
      *(ushort4*)(Orow + ni * 16 + g * 4) = o4;
    }
  }
}

extern "C" void kernel_launch(void* const* d_in, const int* in_sizes, int n_in,
                              void* d_out, int out_size, void* d_ws, size_t ws_size,
                              hipStream_t stream) {
  const float* x       = (const float*)d_in[0];
  const float* Wq      = (const float*)d_in[1];
  const float* bq      = (const float*)d_in[2];
  const float* Wk      = (const float*)d_in[3];
  const float* bk      = (const float*)d_in[4];
  // d_in[5] Wvq, d_in[6] bvq, d_in[7] v_keys: dead (top_k selects all NVK)
  const float* v_embed = (const float*)d_in[8];
  const float* Wo      = (const float*)d_in[9];
  const float* bo      = (const float*)d_in[10];
  float* out = (float*)d_out;

  char* w = (char*)d_ws;
  unsigned short* xb  = (unsigned short*)w; w += (size_t)kBT * kD * 2;  // 16MB
  unsigned short* qb  = (unsigned short*)w; w += (size_t)kBT * kD * 2;
  unsigned short* kb  = (unsigned short*)w; w += (size_t)kBT * kD * 2;
  unsigned short* ob  = (unsigned short*)w; w += (size_t)kBT * kD * 2;
  unsigned short* vtb = (unsigned short*)w; w += (size_t)kBT * kD * 2;
  unsigned short* wqb = (unsigned short*)w; w += (size_t)kD * kD * 2;   // 8MB
  unsigned short* wkb = (unsigned short*)w; w += (size_t)kD * kD * 2;
  unsigned short* wob = (unsigned short*)w; w += (size_t)kD * kD * 2;

  // fused prep: make_vt (+x->bf16 reuse of the x read) + 3 weight converts
  prep_kernel<<<dim3(1024 + 3 * 4096), 256, 0, stream>>>(
      x, v_embed, Wq, Wk, Wo, vtb, xb, wqb, wkb, wob);

  // fold softmax scale (1/sqrt(HD) * log2(e), exp2 domain) into Q projection
  const float scaleQ = 0.08838834764831845f * 1.4426950408889634f;
  // fused Q+K projections: grid.z picks weights/bias/output
  gemm_bt<4, true, true><<<dim3(kD / 128, kBT / 128, 2), 256, 0, stream>>>(
      xb, wqb, wkb, bq, bk, qb, kb, scaleQ, 1.0f);

  attn2_kernel<<<dim3(512), 256, 0, stream>>>(qb, kb, vtb, ob);

  // out-projection: 128x64 tiles -> 1024 blocks = 4/CU (128x128 gave 512 = 2/CU)
  gemm_bt<2, false, false><<<dim3(kD / 64, kBT / 128, 1), 256, 0, stream>>>(
      ob, wob, nullptr, bo, nullptr, out, nullptr, 1.0f, 1.0f);
}

// Round 7
// 316.375 us; speedup vs baseline: 1.0164x; 1.0164x over previous
//
#include <hip/hip_runtime.h>
#include <hip/hip_bf16.h>

#define DEV __device__ __forceinline__

typedef __bf16 bf16x8 __attribute__((ext_vector_type(8)));
typedef __bf16 bf16x4 __attribute__((ext_vector_type(4)));
typedef float f32x4 __attribute__((ext_vector_type(4)));

static constexpr int kB = 2, kT = 2048, kD = 2048, kH = 16, kHD = 128;
static constexpr int kBT = kB * kT;  // 4096

// fast 2^x: v_exp_f32 computes exp2 natively on gfx950
#if __has_builtin(__builtin_amdgcn_exp2f)
DEV float fast_exp2(float x) { return __builtin_amdgcn_exp2f(x); }
#else
DEV float fast_exp2(float x) { return exp2f(x); }
#endif

DEV unsigned short f2bf(float f) {
  union { __hip_bfloat16 h; unsigned short u; } cv;
  cv.h = __float2bfloat16(f);
  return cv.u;
}

// async global->LDS, 16B per lane. LDS dest must be wave-uniform base + lane*16.
DEV void gl_lds16(const void* g, void* l) {
  __builtin_amdgcn_global_load_lds(
      (const __attribute__((address_space(1))) unsigned int*)g,
      (__attribute__((address_space(3))) unsigned int*)l, 16, 0, 0);
}

#define MFMA(a, b, c) __builtin_amdgcn_mfma_f32_16x16x32_bf16(a, b, c, 0, 0, 0)

// bank swizzle for [rows]x32 bf16 tiles staged via global_load_lds:
// slot = row*4 + (chunk ^ swz(row)); swz covers row bits 0..3 so frag-read
// lanes {i,i+4,i+8,i+12} land in distinct 16B chunks -> 2-way max (free).
DEV int swz4(int row) { return (row ^ (row >> 2)) & 3; }

// ---------------- fused prep: make_vt + x->bf16 + 3 weight converts ---------
// blocks [0,1024): make_vt for (t0,h,b); ALSO emits xb for its x-patch
//   (x is loaded here anyway -> saves the 64MB fp32 re-read cvt4 did).
// blocks [1024,13312): fp32->bf16 convert of Wq/Wk/Wo (4096 blocks each).
__global__ __launch_bounds__(256) void prep_kernel(
    const float* __restrict__ x, const float* __restrict__ v_embed,
    const float* __restrict__ Wq, const float* __restrict__ Wk,
    const float* __restrict__ Wo, unsigned short* __restrict__ vt,
    unsigned short* __restrict__ xb, unsigned short* __restrict__ wqb,
    unsigned short* __restrict__ wkb, unsigned short* __restrict__ wob) {
  const int tid = threadIdx.x;
  const int bx = blockIdx.x;
  if (bx >= 1024) {
    // ---- weight convert: 3 x (kD*kD/4 float4), 4096 blocks each ----
    const int j = bx - 1024;
    const int which = j >> 12;             // 0..2
    const int i = (j & 4095) * 256 + tid;  // < kD*kD/4 exactly
    const float* s = which == 0 ? Wq : which == 1 ? Wk : Wo;
    unsigned short* d = which == 0 ? wqb : which == 1 ? wkb : wob;
    float4 v = ((const float4*)s)[i];
    ushort4 o;
    o.x = f2bf(v.x); o.y = f2bf(v.y); o.z = f2bf(v.z); o.w = f2bf(v.w);
    ((ushort4*)d)[i] = o;
    return;
  }
  // ---- make_vt: V^T = (x * c) transposed to [b][h][hd][T], bf16 ----
  // top_k with TOPK==NVK==4 selects ALL rows -> c[d] = 2*sum_{k<4} v_embed[k][d].
  __shared__ __align__(16) unsigned short sT[128 * 72];  // [hd][t], stride 72
  const int t0 = (bx & 31) * 64, h = (bx >> 5) & 15, b = bx >> 9;
  const int d4 = tid & 31, r8 = tid >> 5;
  const int dg = h * kHD + d4 * 4;
  float4 e0 = *(const float4*)(v_embed + dg);
  float4 e1 = *(const float4*)(v_embed + kD + dg);
  float4 e2 = *(const float4*)(v_embed + 2 * kD + dg);
  float4 e3 = *(const float4*)(v_embed + 3 * kD + dg);
  float4 c4;
  c4.x = 2.f * (e0.x + e1.x + e2.x + e3.x);
  c4.y = 2.f * (e0.y + e1.y + e2.y + e3.y);
  c4.z = 2.f * (e0.z + e1.z + e2.z + e3.z);
  c4.w = 2.f * (e0.w + e1.w + e2.w + e3.w);
#pragma unroll
  for (int it = 0; it < 8; it++) {
    const int t = r8 + it * 8;  // 0..63
    const size_t row = (size_t)(b * kT + t0 + t) * kD + dg;
    float4 v = *(const float4*)(x + row);
    // x -> bf16 (was a separate full read of x in cvt4)
    ushort4 xo;
    xo.x = f2bf(v.x); xo.y = f2bf(v.y); xo.z = f2bf(v.z); xo.w = f2bf(v.w);
    *(ushort4*)(xb + row) = xo;
    sT[(d4 * 4 + 0) * 72 + t] = f2bf(v.x * c4.x);
    sT[(d4 * 4 + 1) * 72 + t] = f2bf(v.y * c4.y);
    sT[(d4 * 4 + 2) * 72 + t] = f2bf(v.z * c4.z);
    sT[(d4 * 4 + 3) * 72 + t] = f2bf(v.w * c4.w);
  }
  __syncthreads();
#pragma unroll
  for (int it = 0; it < 4; it++) {
    const int hd = (tid >> 3) + it * 32;
    const int tt = (tid & 7) * 8;
    bf16x8 vv = *(const bf16x8*)(sT + hd * 72 + tt);
    *(bf16x8*)(vt + ((size_t)((b * kH + h) * kHD + hd)) * kT + t0 + tt) = vv;
  }
}

// ---------------- C[m,n] = (sum_k A[m,k]*B[n,k] + bias[n]) * scale ----------
// 128 x (NREP*32) tile, BK=64 (two independent 128x32 sub-tiles, verified swz4
// layout per sub-tile), 4 waves (2x2), 16x16x32 bf16 MFMA, global_load_lds
// w=16. 2 barriers per NREP*8 MFMA. Inter-block overlap covers the barrier
// drain (m114).
// NREP history: out-proj NREP=2 @1024 blocks (round 6) and M-split (round 3)
// both LOST to NREP=4 @512 blocks — don't re-try small tiles for it.
// T1 XCD swizzle (round-5: FETCH 133->64MB, -5 us): HW XCD = linear_blk % 8;
// remap so each XCD owns a compact tile region (bijective per grid shape).
template <int NREP, bool BF16OUT, bool FUSED2>
__global__ __launch_bounds__(256, 4) void gemm_bt(
    const unsigned short* __restrict__ A, const unsigned short* __restrict__ B1,
    const unsigned short* __restrict__ B2, const float* __restrict__ bias1,
    const float* __restrict__ bias2, void* __restrict__ C1, void* __restrict__ C2,
    float scale1, float scale2) {
  constexpr int BN = NREP * 32;
  constexpr int N = kD, K = kD;
  __shared__ __align__(16) unsigned short As[2][128 * 32], Bs[2][BN * 32];
  int bxn, byn, bzn;
  if constexpr (FUSED2) {
    // grid (16,32,2) = 1024 blocks; per-XCD region: z fixed, 8 n-tiles, 16 m.
    const int lb = blockIdx.x + (blockIdx.y << 4) + (blockIdx.z << 9);
    const int xcd = lb & 7, r = lb >> 3;  // r in [0,128)
    bzn = xcd & 1;
    bxn = (((xcd >> 1) & 1) << 3) + (r & 7);  // n-tile 0..15
    byn = ((xcd >> 2) << 4) + (r >> 3);       // m-tile 0..31
  } else if constexpr (NREP == 2) {
    // grid (32,32,1) = 1024 blocks; per-XCD region: 8 n-tiles x 16 m-tiles.
    const int lb = blockIdx.x + (blockIdx.y << 5);
    const int xcd = lb & 7, r = lb >> 3;  // r in [0,128)
    bzn = 0;
    bxn = ((xcd & 3) << 3) + (r & 7);    // n-tile 0..31
    byn = ((xcd >> 2) << 4) + (r >> 3);  // m-tile 0..31
  } else {
    // grid (16,32,1) = 512 blocks; per-XCD region: 8 n-tiles x 8 m-tiles.
    const int lb = blockIdx.x + (blockIdx.y << 4);
    const int xcd = lb & 7, r = lb >> 3;  // r in [0,64)
    bzn = 0;
    bxn = ((xcd & 1) << 3) + (r & 7);
    byn = ((xcd >> 1) << 3) + (r >> 3);
  }
  const unsigned short* Bm = (FUSED2 && bzn) ? B2 : B1;
  const float* bias = (FUSED2 && bzn) ? bias2 : bias1;
  void* Cout = (FUSED2 && bzn) ? C2 : C1;
  const float scale = (FUSED2 && bzn) ? scale2 : scale1;
  const int tid = threadIdx.x;
  const int lane = tid & 63, wave = tid >> 6;
  const int wr = wave >> 1, wc = wave & 1;
  const int m0 = byn * 128, n0 = bxn * BN;
  const int frow = lane & 15, fc = lane >> 4;

  f32x4 acc[4][NREP];
#pragma unroll
  for (int i = 0; i < 4; i++)
#pragma unroll
    for (int j = 0; j < NREP; j++)
#pragma unroll
      for (int r = 0; r < 4; r++) acc[i][j][r] = 0.f;

  const int r0 = tid >> 2, c0 = (tid & 3) ^ swz4(r0);
  const int p1 = tid + 256;
  const int r1 = p1 >> 2, c1 = (p1 & 3) ^ swz4(r1);

  const unsigned short* Ab = A + (size_t)m0 * K;
  const unsigned short* Bb = Bm + (size_t)n0 * K;

  for (int k0 = 0; k0 < K; k0 += 64) {
    __syncthreads();
#pragma unroll
    for (int hh = 0; hh < 2; hh++) {
      const int kk = k0 + hh * 32;
      gl_lds16(Ab + (size_t)r0 * K + kk + c0 * 8, &As[hh][tid * 8]);
      gl_lds16(Ab + (size_t)r1 * K + kk + c1 * 8, &As[hh][p1 * 8]);
      gl_lds16(Bb + (size_t)r0 * K + kk + c0 * 8, &Bs[hh][tid * 8]);
      if constexpr (NREP == 4)
        gl_lds16(Bb + (size_t)r1 * K + kk + c1 * 8, &Bs[hh][p1 * 8]);
    }
    __syncthreads();
#pragma unroll
    for (int hh = 0; hh < 2; hh++) {
      bf16x8 af[4], bfr[NREP];
#pragma unroll
      for (int mi = 0; mi < 4; mi++) {
        int row = wr * 64 + mi * 16 + frow;
        af[mi] = *(const bf16x8*)(&As[hh][(row * 4 + (fc ^ swz4(row))) * 8]);
      }
#pragma unroll
      for (int ni = 0; ni < NREP; ni++) {
        int row = wc * (NREP * 16) + ni * 16 + frow;
        bfr[ni] = *(const bf16x8*)(&Bs[hh][(row * 4 + (fc ^ swz4(row))) * 8]);
      }
#pragma unroll
      for (int mi = 0; mi < 4; mi++)
#pragma unroll
        for (int ni = 0; ni < NREP; ni++)
          acc[mi][ni] = MFMA(af[mi], bfr[ni], acc[mi][ni]);
    }
  }
  // epilogue: C/D layout col=lane&15, row=(lane>>4)*4+reg
#pragma unroll
  for (int ni = 0; ni < NREP; ni++) {
    const int n = n0 + wc * (NREP * 16) + ni * 16 + frow;
    const float bs = bias[n];
#pragma unroll
    for (int mi = 0; mi < 4; mi++) {
      const int mb = m0 + wr * 64 + mi * 16 + fc * 4;
#pragma unroll
      for (int r = 0; r < 4; r++) {
        const float v = (acc[mi][ni][r] + bs) * scale;
        if (BF16OUT)
          ((unsigned short*)Cout)[(size_t)(mb + r) * N + n] = f2bf(v);
        else
          ((float*)Cout)[(size_t)(mb + r) * N + n] = v;
      }
    }
  }
}

// ---------------- flash attention v2, causal, S^T formulation ----------------
// Q is PRE-SCALED by (1/sqrt(HD))*log2(e); softmax in exp2 domain.
// 1-D grid 512, XCD-swizzled: all 16 pi-blocks of one (b,h) land on one XCD
// (bid&7 = XCD round-robin) so K/V (1MB) is fetched into that L2 once.
// Each block: paired q-tiles (31-pi, pi) -> uniform 33 k-tile units.
// T13 defer-max (wave-uniform, LOCAL-max test): if every lane's per-lane max
// is within THR of the running row max, the global row max is too -> keep
// m_i, skip BOTH critical-path shfl_xor reduces AND the 32-mul O-rescale.
// P bounded by 2^THR (bf16/f32 headroom fine). First tile always full path.
// NOTE: setprio here measured net-negative (lockstep 4-wave = m190 regime).
__global__ __launch_bounds__(256, 2) void attn2_kernel(
    const unsigned short* __restrict__ Q, const unsigned short* __restrict__ Kg,
    const unsigned short* __restrict__ Vt, unsigned short* __restrict__ O) {
  __shared__ __align__(16) unsigned short sK[2][64 * 128];  // [key][hd], swizzled
  __shared__ __align__(16) unsigned short sV[2][64 * 128];  // [hd][key], swizzled
  const int tid = threadIdx.x, l = tid & 63, w = tid >> 6;
  const int g = l >> 4, q15 = l & 15;
  const int bid = blockIdx.x;
  const int xcd = bid & 7, rest = bid >> 3;
  const int gidx = xcd + 8 * (rest & 3);  // (b,h) group 0..31
  const int pi = rest >> 2;               // 0..15
  const int h = gidx & 15, b = gidx >> 4;

  for (int half = 0; half < 2; half++) {
    const int qt = half == 0 ? (31 - pi) : pi;
    const int q0 = qt * 64;
    const int nkb = qt + 1;
    const int q = q0 + w * 16 + q15;  // this lane's q column

    __syncthreads();  // buffer reuse safety across halves
    // stage tile 0 -> buf 0
    for (int i = 0; i < 4; i++) {
      const int idx = tid + i * 256;
      const int key = idx >> 4, cc = (idx & 15) ^ (key & 15);
      gl_lds16(Kg + (size_t)(b * kT + key) * kD + h * kHD + cc * 8,
               &sK[0][idx * 8]);
    }
    for (int i = 0; i < 4; i++) {
      const int idx = tid + i * 256;
      const int hd = idx >> 3;
      const int cc = (idx & 7) ^ (hd & 7) ^ (((hd >> 3) & 1) << 2);
      gl_lds16(Vt + ((size_t)((b * kH + h) * kHD + hd)) * kT + cc * 8,
               &sV[0][idx * 8]);
    }

    // Q B-frags (lane holds Q[q][hd = kk*32 + g*8 .. +7])
    bf16x8 qf[4];
    const unsigned short* Qrow = Q + (size_t)(b * kT + q) * kD + h * kHD;
#pragma unroll
    for (int kk = 0; kk < 4; kk++)
      qf[kk] = *(const bf16x8*)(Qrow + kk * 32 + g * 8);

    f32x4 oacc[8];
#pragma unroll
    for (int ni = 0; ni < 8; ni++)
      for (int r = 0; r < 4; r++) oacc[ni][r] = 0.f;
    float m_i = -1e30f, l_i = 0.f;

    for (int kb = 0; kb < nkb; kb++) {
      const int bb = kb & 1;
      __syncthreads();  // drains prefetch(kb) [compiler vmcnt], syncs buffers
      if (kb + 1 < nkb) {
        const int k0n = (kb + 1) * 64;
        const int nb = 1 - bb;
#pragma unroll
        for (int i = 0; i < 4; i++) {
          const int idx = tid + i * 256;
          const int key = idx >> 4, cc = (idx & 15) ^ (key & 15);
          gl_lds16(Kg + (size_t)(b * kT + k0n + key) * kD + h * kHD + cc * 8,
                   &sK[nb][idx * 8]);
        }
#pragma unroll
        for (int i = 0; i < 4; i++) {
          const int idx = tid + i * 256;
          const int hd = idx >> 3;
          const int cc = (idx & 7) ^ (hd & 7) ^ (((hd >> 3) & 1) << 2);
          gl_lds16(Vt + ((size_t)((b * kH + h) * kHD + hd)) * kT + k0n + cc * 8,
                   &sV[nb][idx * 8]);
        }
      }

      // S^T = K Q^T : lane holds S^T[key = s*16 + g*4 + r][q]
      f32x4 st[4];
#pragma unroll
      for (int s = 0; s < 4; s++)
        for (int r = 0; r < 4; r++) st[s][r] = 0.f;
#pragma unroll
      for (int s = 0; s < 4; s++) {
        const int key = s * 16 + q15;  // A-frag row for this lane
#pragma unroll
        for (int kk = 0; kk < 4; kk++) {
          bf16x8 kf = *(const bf16x8*)(
              &sK[bb][(key * 16 + ((kk * 4 + g) ^ (key & 15))) * 8]);
          st[s] = MFMA(kf, qf[kk], st[s]);
        }
      }
      // causal mask (diagonal tile only)
      if (kb == nkb - 1) {
        const int k0 = kb * 64;
#pragma unroll
        for (int s = 0; s < 4; s++)
          for (int r = 0; r < 4; r++)
            if (k0 + s * 16 + g * 4 + r > q) st[s][r] = -1e30f;
      }
      // online softmax (exp2 domain; Q pre-scaled). Per-lane row stats.
      float mx = -1e30f;
#pragma unroll
      for (int s = 0; s < 4; s++)
        for (int r = 0; r < 4; r++) mx = fmaxf(mx, st[s][r]);
      // T13 defer-max on LOCAL max: wave-uniform branch, common case skips
      // the two serial shfl_xor reduces and the O-rescale entirely.
      const bool defer = __all(mx - m_i <= 8.0f);
      float mn, alpha;
      if (defer) {
        mn = m_i;
        alpha = 1.f;
      } else {
        mx = fmaxf(mx, __shfl_xor(mx, 16, 64));
        mx = fmaxf(mx, __shfl_xor(mx, 32, 64));
        mn = fmaxf(m_i, mx);
        alpha = fast_exp2(m_i - mn);
      }
      float rs = 0.f;
      union { bf16x8 v; unsigned short u[8]; } pkv[2];
#pragma unroll
      for (int s = 0; s < 4; s++)
        for (int r = 0; r < 4; r++) {
          const float p = fast_exp2(st[s][r] - mn);
          rs += p;
          pkv[s >> 1].u[(s & 1) * 4 + r] = f2bf(p);  // slot j=(s&1)*4+r
        }
      rs += __shfl_xor(rs, 16, 64);
      rs += __shfl_xor(rs, 32, 64);
      m_i = mn;
      l_i = l_i * alpha + rs;
      if (!defer) {
#pragma unroll
        for (int ni = 0; ni < 8; ni++)
          for (int r = 0; r < 4; r++) oacc[ni][r] *= alpha;
      }
      // O^T += V^T P^T with K=32 MFMA; A-frag slot (g,j) = key 32c+(j>>2)*16+4g+(j&3)
#pragma unroll
      for (int ni = 0; ni < 8; ni++) {
        const int hd = ni * 16 + q15;
        const int hx = (hd & 7) ^ (((hd >> 3) & 1) << 2), base = hd * 8;
#pragma unroll
        for (int c = 0; c < 2; c++) {
          const int c4l = 8 * c + g;       // keys 32c+4g+0..3   (j=0..3)
          const int c4h = 8 * c + 4 + g;   // keys 32c+16+4g+0..3 (j=4..7)
          bf16x4 lo = *(const bf16x4*)(
              &sV[bb][(base + ((c4l >> 1) ^ hx)) * 8 + (c4l & 1) * 4]);
          bf16x4 hi = *(const bf16x4*)(
              &sV[bb][(base + ((c4h >> 1) ^ hx)) * 8 + (c4h & 1) * 4]);
          bf16x8 vf = __builtin_shufflevector(lo, hi, 0, 1, 2, 3, 4, 5, 6, 7);
          oacc[ni] = MFMA(vf, pkv[c].v, oacc[ni]);
        }
      }
    }
    // epilogue: O^T C-layout -> O[b][t=q][h*128 + hd], 4 contiguous d per lane
    const float inv = 1.f / l_i;
    unsigned short* Orow = O + (size_t)(b * kT + q) * kD + h * kHD;
#pragma unroll
    for (int ni = 0; ni < 8; ni++) {
      ushort4 o4;
      o4.x = f2bf(oacc[ni][0] * inv);
      o4.y = f2bf(oacc[ni][1] * inv);
      o4.z = f2bf(oacc[ni][2] * inv);
      o4.w = f2bf(oacc[ni][3] * inv);
      *(ushort4*)(Orow + ni * 16 + g * 4) = o4;
    }
  }
}

extern "C" void kernel_launch(void* const* d_in, const int* in_sizes, int n_in,
                              void* d_out, int out_size, void* d_ws, size_t ws_size,
                              hipStream_t stream) {
  const float* x       = (const float*)d_in[0];
  const float* Wq      = (const float*)d_in[1];
  const float* bq      = (const float*)d_in[2];
  const float* Wk      = (const float*)d_in[3];
  const float* bk      = (const float*)d_in[4];
  // d_in[5] Wvq, d_in[6] bvq, d_in[7] v_keys: dead (top_k selects all NVK)
  const float* v_embed = (const float*)d_in[8];
  const float* Wo      = (const float*)d_in[9];
  const float* bo      = (const float*)d_in[10];
  float* out = (float*)d_out;

  char* w = (char*)d_ws;
  unsigned short* xb  = (unsigned short*)w; w += (size_t)kBT * kD * 2;  // 16MB
  unsigned short* qb  = (unsigned short*)w; w += (size_t)kBT * kD * 2;
  unsigned short* kb  = (unsigned short*)w; w += (size_t)kBT * kD * 2;
  unsigned short* ob  = (unsigned short*)w; w += (size_t)kBT * kD * 2;
  unsigned short* vtb = (unsigned short*)w; w += (size_t)kBT * kD * 2;
  unsigned short* wqb = (unsigned short*)w; w += (size_t)kD * kD * 2;   // 8MB
  unsigned short* wkb = (unsigned short*)w; w += (size_t)kD * kD * 2;
  unsigned short* wob = (unsigned short*)w; w += (size_t)kD * kD * 2;

  // fused prep: make_vt (+x->bf16 reuse of the x read) + 3 weight converts
  prep_kernel<<<dim3(1024 + 3 * 4096), 256, 0, stream>>>(
      x, v_embed, Wq, Wk, Wo, vtb, xb, wqb, wkb, wob);

  // fold softmax scale (1/sqrt(HD) * log2(e), exp2 domain) into Q projection
  const float scaleQ = 0.08838834764831845f * 1.4426950408889634f;
  // fused Q+K projections: grid.z picks weights/bias/output
  gemm_bt<4, true, true><<<dim3(kD / 128, kBT / 128, 2), 256, 0, stream>>>(
      xb, wqb, wkb, bq, bk, qb, kb, scaleQ, 1.0f);

  attn2_kernel<<<dim3(512), 256, 0, stream>>>(qb, kb, vtb, ob);

  // out-projection: 128x128 @ 512 blocks (best-known; small-tile variants lost)
  gemm_bt<4, false, false><<<dim3(kD / 128, kBT / 128, 1), 256, 0, stream>>>(
      ob, wob, nullptr, bo, nullptr, out, nullptr, 1.0f, 1.0f);
}

// Round 9
// 308.823 us; speedup vs baseline: 1.0412x; 1.0245x over previous
//
#include <hip/hip_runtime.h>
#include <hip/hip_bf16.h>

#define DEV __device__ __forceinline__

typedef __bf16 bf16x8 __attribute__((ext_vector_type(8)));
typedef __bf16 bf16x4 __attribute__((ext_vector_type(4)));
typedef float f32x4 __attribute__((ext_vector_type(4)));

static constexpr int kB = 2, kT = 2048, kD = 2048, kH = 16, kHD = 128;
static constexpr int kBT = kB * kT;  // 4096

// fast 2^x: v_exp_f32 computes exp2 natively on gfx950
#if __has_builtin(__builtin_amdgcn_exp2f)
DEV float fast_exp2(float x) { return __builtin_amdgcn_exp2f(x); }
#else
DEV float fast_exp2(float x) { return exp2f(x); }
#endif

DEV unsigned short f2bf(float f) {
  union { __hip_bfloat16 h; unsigned short u; } cv;
  cv.h = __float2bfloat16(f);
  return cv.u;
}

// async global->LDS, 16B per lane. LDS dest must be wave-uniform base + lane*16.
DEV void gl_lds16(const void* g, void* l) {
  __builtin_amdgcn_global_load_lds(
      (const __attribute__((address_space(1))) unsigned int*)g,
      (__attribute__((address_space(3))) unsigned int*)l, 16, 0, 0);
}

#define MFMA(a, b, c) __builtin_amdgcn_mfma_f32_16x16x32_bf16(a, b, c, 0, 0, 0)

// bank swizzle for [rows]x32 bf16 tiles staged via global_load_lds:
// slot = row*4 + (chunk ^ swz(row)); swz covers row bits 0..3 so frag-read
// lanes {i,i+4,i+8,i+12} land in distinct 16B chunks -> 2-way max (free).
DEV int swz4(int row) { return (row ^ (row >> 2)) & 3; }

// ---------------- fused prep: make_vt + x->bf16 + 3 weight converts ---------
// blocks [0,1024): make_vt for (t0,h,b); ALSO emits xb for its x-patch
//   (x is loaded here anyway -> saves the 64MB fp32 re-read cvt4 did).
// blocks [1024,13312): fp32->bf16 convert of Wq/Wk/Wo (4096 blocks each).
__global__ __launch_bounds__(256) void prep_kernel(
    const float* __restrict__ x, const float* __restrict__ v_embed,
    const float* __restrict__ Wq, const float* __restrict__ Wk,
    const float* __restrict__ Wo, unsigned short* __restrict__ vt,
    unsigned short* __restrict__ xb, unsigned short* __restrict__ wqb,
    unsigned short* __restrict__ wkb, unsigned short* __restrict__ wob) {
  const int tid = threadIdx.x;
  const int bx = blockIdx.x;
  if (bx >= 1024) {
    // ---- weight convert: 3 x (kD*kD/4 float4), 4096 blocks each ----
    const int j = bx - 1024;
    const int which = j >> 12;             // 0..2
    const int i = (j & 4095) * 256 + tid;  // < kD*kD/4 exactly
    const float* s = which == 0 ? Wq : which == 1 ? Wk : Wo;
    unsigned short* d = which == 0 ? wqb : which == 1 ? wkb : wob;
    float4 v = ((const float4*)s)[i];
    ushort4 o;
    o.x = f2bf(v.x); o.y = f2bf(v.y); o.z = f2bf(v.z); o.w = f2bf(v.w);
    ((ushort4*)d)[i] = o;
    return;
  }
  // ---- make_vt: V^T = (x * c) transposed to [b][h][hd][T], bf16 ----
  // top_k with TOPK==NVK==4 selects ALL rows -> c[d] = 2*sum_{k<4} v_embed[k][d].
  __shared__ __align__(16) unsigned short sT[128 * 72];  // [hd][t], stride 72
  const int t0 = (bx & 31) * 64, h = (bx >> 5) & 15, b = bx >> 9;
  const int d4 = tid & 31, r8 = tid >> 5;
  const int dg = h * kHD + d4 * 4;
  float4 e0 = *(const float4*)(v_embed + dg);
  float4 e1 = *(const float4*)(v_embed + kD + dg);
  float4 e2 = *(const float4*)(v_embed + 2 * kD + dg);
  float4 e3 = *(const float4*)(v_embed + 3 * kD + dg);
  float4 c4;
  c4.x = 2.f * (e0.x + e1.x + e2.x + e3.x);
  c4.y = 2.f * (e0.y + e1.y + e2.y + e3.y);
  c4.z = 2.f * (e0.z + e1.z + e2.z + e3.z);
  c4.w = 2.f * (e0.w + e1.w + e2.w + e3.w);
#pragma unroll
  for (int it = 0; it < 8; it++) {
    const int t = r8 + it * 8;  // 0..63
    const size_t row = (size_t)(b * kT + t0 + t) * kD + dg;
    float4 v = *(const float4*)(x + row);
    // x -> bf16 (was a separate full read of x in cvt4)
    ushort4 xo;
    xo.x = f2bf(v.x); xo.y = f2bf(v.y); xo.z = f2bf(v.z); xo.w = f2bf(v.w);
    *(ushort4*)(xb + row) = xo;
    sT[(d4 * 4 + 0) * 72 + t] = f2bf(v.x * c4.x);
    sT[(d4 * 4 + 1) * 72 + t] = f2bf(v.y * c4.y);
    sT[(d4 * 4 + 2) * 72 + t] = f2bf(v.z * c4.z);
    sT[(d4 * 4 + 3) * 72 + t] = f2bf(v.w * c4.w);
  }
  __syncthreads();
#pragma unroll
  for (int it = 0; it < 4; it++) {
    const int hd = (tid >> 3) + it * 32;
    const int tt = (tid & 7) * 8;
    bf16x8 vv = *(const bf16x8*)(sT + hd * 72 + tt);
    *(bf16x8*)(vt + ((size_t)((b * kH + h) * kHD + hd)) * kT + t0 + tt) = vv;
  }
}

// ------- QK projection: 256x256-tile 8-phase pipelined GEMM (m201 port) -----
// C[m,n] = (sum_k A[m,k]*B[n,k] + bias[n]) * scale, bf16 out, fused Q+K via z.
// 512 thr = 8 waves (2x4), per-wave 128x64 out, acc[8][4]. BK=32 sub-tile ring
// of 4 LDS buffers (128KB, 1 block/CU). Stage depth 3 sub-tiles; per sub-tile
// 2 phases {ds_read frags | 2 gl_lds stage | s_barrier | lgkmcnt(0) |
// sched_barrier | setprio(1) 16 MFMA setprio(0) | s_barrier}.
// Counted vmcnt ONCE per sub-tile, never 0 in steady state: outstanding =
// {k+1,k+2,k+3} x 4 loads = 12 -> vmcnt(8) retires exactly k+1's; the
// FOLLOWING s_barrier makes that cross-wave safe. Tail: vmcnt(4) at NT-3,
// vmcnt(0) at NT-2. NO __syncthreads (would emit the vmcnt(0) drain).
// swz4 staging/frag addressing identical to verified gemm_bt per 32-col tile.
__global__ __launch_bounds__(512, 2) void gemm8p_qk(
    const unsigned short* __restrict__ A, const unsigned short* __restrict__ B1,
    const unsigned short* __restrict__ B2, const float* __restrict__ bias1,
    const float* __restrict__ bias2, unsigned short* __restrict__ C1,
    unsigned short* __restrict__ C2, float scale1, float scale2) {
  constexpr int N = kD, K = kD;
  constexpr int NT = K / 32;  // 64 sub-tiles
  __shared__ __align__(16) unsigned short As[4][256 * 32];
  __shared__ __align__(16) unsigned short Bs[4][256 * 32];
  // XCD swizzle: grid (8,16,2) = 256 blocks = 1/CU; xcd = linear % 8.
  // Each XCD: one z, 4 m-tiles x 8 n-tiles (compact region). Bijective.
  const int lb = blockIdx.x + (blockIdx.y << 3) + (blockIdx.z << 7);
  const int xcd = lb & 7, r2 = lb >> 3;  // r2 in [0,32)
  const int bzn = xcd & 1;
  const int byn = ((xcd >> 1) << 2) + (r2 >> 3);  // 0..15
  const int bxn = r2 & 7;                         // 0..7
  const unsigned short* Bm = bzn ? B2 : B1;
  const float* bias = bzn ? bias2 : bias1;
  unsigned short* Cout = bzn ? C2 : C1;
  const float scale = bzn ? scale2 : scale1;

  const int tid = threadIdx.x;
  const int lane = tid & 63, wave = tid >> 6;
  const int wr = wave >> 2, wc = wave & 3;  // 2 x 4 wave grid
  const int m0 = byn * 256, n0 = bxn * 256;
  const int frow = lane & 15, fc = lane >> 4;

  f32x4 acc[8][4];
#pragma unroll
  for (int i = 0; i < 8; i++)
#pragma unroll
    for (int j = 0; j < 4; j++)
#pragma unroll
      for (int r = 0; r < 4; r++) acc[i][j][r] = 0.f;

  // staging slots: sub-tile = 256 rows x 32 cols bf16 = 1024 x 16B chunks
  const int q0 = tid, q1 = tid + 512;
  const int r0 = q0 >> 2, c0 = (q0 & 3) ^ swz4(r0);
  const int r1 = q1 >> 2, c1 = (q1 & 3) ^ swz4(r1);

  const unsigned short* Ab = A + (size_t)m0 * K;
  const unsigned short* Bb = Bm + (size_t)n0 * K;

  auto stA = [&](int bf, int k0) {
    gl_lds16(Ab + (size_t)r0 * K + k0 + c0 * 8, &As[bf][q0 * 8]);
    gl_lds16(Ab + (size_t)r1 * K + k0 + c1 * 8, &As[bf][q1 * 8]);
  };
  auto stB = [&](int bf, int k0) {
    gl_lds16(Bb + (size_t)r0 * K + k0 + c0 * 8, &Bs[bf][q0 * 8]);
    gl_lds16(Bb + (size_t)r1 * K + k0 + c1 * 8, &Bs[bf][q1 * 8]);
  };

  // prologue: stage sub-tiles 0,1,2 (12 loads); wait tile 0 (keep 8 in flight)
  stA(0, 0); stB(0, 0);
  stA(1, 32); stB(1, 32);
  stA(2, 64); stB(2, 64);
  asm volatile("s_waitcnt vmcnt(8)" ::: "memory");
  __builtin_amdgcn_s_barrier();
  __builtin_amdgcn_sched_barrier(0);

  for (int k = 0; k < NT; ++k) {
    const int buf = k & 3;
    const int nbuf = (k + 3) & 3;
    const int kn = (k + 3) * 32;
    const bool pre = (k + 3) < NT;
    const unsigned short* Asb = As[buf];
    const unsigned short* Bsb = Bs[buf];

    // ---- phase A: B frags + A-lo frags; stage A(k+3) ----
    bf16x8 bfr[4], af[4];
#pragma unroll
    for (int ni = 0; ni < 4; ni++) {
      const int row = wc * 64 + ni * 16 + frow;
      bfr[ni] = *(const bf16x8*)(Bsb + (row * 4 + (fc ^ swz4(row))) * 8);
    }
#pragma unroll
    for (int mi = 0; mi < 4; mi++) {
      const int row = wr * 128 + mi * 16 + frow;
      af[mi] = *(const bf16x8*)(Asb + (row * 4 + (fc ^ swz4(row))) * 8);
    }
    if (pre) stA(nbuf, kn);
    __builtin_amdgcn_s_barrier();
    asm volatile("s_waitcnt lgkmcnt(0)" ::: "memory");
    __builtin_amdgcn_sched_barrier(0);
    __builtin_amdgcn_s_setprio(1);
#pragma unroll
    for (int mi = 0; mi < 4; mi++)
#pragma unroll
      for (int ni = 0; ni < 4; ni++)
        acc[mi][ni] = MFMA(af[mi], bfr[ni], acc[mi][ni]);
    __builtin_amdgcn_s_setprio(0);
    __builtin_amdgcn_s_barrier();
    __builtin_amdgcn_sched_barrier(0);

    // ---- phase B: A-hi frags; stage B(k+3); counted vmcnt (never 0 hot) ----
    bf16x8 af2[4];
#pragma unroll
    for (int mi = 0; mi < 4; mi++) {
      const int row = wr * 128 + (mi + 4) * 16 + frow;
      af2[mi] = *(const bf16x8*)(Asb + (row * 4 + (fc ^ swz4(row))) * 8);
    }
    if (pre) stB(nbuf, kn);
    if (k < NT - 3)
      asm volatile("s_waitcnt vmcnt(8)" ::: "memory");  // retire k+1's 4 loads
    else if (k == NT - 3)
      asm volatile("s_waitcnt vmcnt(4)" ::: "memory");
    else if (k == NT - 2)
      asm volatile("s_waitcnt vmcnt(0)" ::: "memory");
    __builtin_amdgcn_s_barrier();
    asm volatile("s_waitcnt lgkmcnt(0)" ::: "memory");
    __builtin_amdgcn_sched_barrier(0);
    __builtin_amdgcn_s_setprio(1);
#pragma unroll
    for (int mi = 0; mi < 4; mi++)
#pragma unroll
      for (int ni = 0; ni < 4; ni++)
        acc[mi + 4][ni] = MFMA(af2[mi], bfr[ni], acc[mi + 4][ni]);
    __builtin_amdgcn_s_setprio(0);
    __builtin_amdgcn_s_barrier();
    __builtin_amdgcn_sched_barrier(0);
  }

  // epilogue: C/D layout col=lane&15, row=(lane>>4)*4+reg (verified mapping)
#pragma unroll
  for (int ni = 0; ni < 4; ni++) {
    const int n = n0 + wc * 64 + ni * 16 + frow;
    const float bs = bias[n];
#pragma unroll
    for (int mi = 0; mi < 8; mi++) {
      const int mb = m0 + wr * 128 + mi * 16 + fc * 4;
#pragma unroll
      for (int r = 0; r < 4; r++) {
        const float v = (acc[mi][ni][r] + bs) * scale;
        Cout[(size_t)(mb + r) * N + n] = f2bf(v);
      }
    }
  }
}

// ---------------- C[m,n] = (sum_k A[m,k]*B[n,k] + bias[n]) * scale ----------
// out-projection kernel: 128x128 tile, BK=64, proven m97-class structure.
// (small-tile / 1024-block variants lost in rounds 3 & 6 — keep 512 @ 2/CU.)
template <int NREP, bool BF16OUT, bool FUSED2>
__global__ __launch_bounds__(256, 4) void gemm_bt(
    const unsigned short* __restrict__ A, const unsigned short* __restrict__ B1,
    const unsigned short* __restrict__ B2, const float* __restrict__ bias1,
    const float* __restrict__ bias2, void* __restrict__ C1, void* __restrict__ C2,
    float scale1, float scale2) {
  constexpr int BN = NREP * 32;
  constexpr int N = kD, K = kD;
  __shared__ __align__(16) unsigned short As[2][128 * 32], Bs[2][BN * 32];
  int bxn, byn, bzn;
  if constexpr (FUSED2) {
    const int lb = blockIdx.x + (blockIdx.y << 4) + (blockIdx.z << 9);
    const int xcd = lb & 7, r = lb >> 3;
    bzn = xcd & 1;
    bxn = (((xcd >> 1) & 1) << 3) + (r & 7);
    byn = ((xcd >> 2) << 4) + (r >> 3);
  } else {
    // grid (16,32,1) = 512 blocks; per-XCD region: 8 n-tiles x 8 m-tiles.
    const int lb = blockIdx.x + (blockIdx.y << 4);
    const int xcd = lb & 7, r = lb >> 3;  // r in [0,64)
    bzn = 0;
    bxn = ((xcd & 1) << 3) + (r & 7);
    byn = ((xcd >> 1) << 3) + (r >> 3);
  }
  const unsigned short* Bm = (FUSED2 && bzn) ? B2 : B1;
  const float* bias = (FUSED2 && bzn) ? bias2 : bias1;
  void* Cout = (FUSED2 && bzn) ? C2 : C1;
  const float scale = (FUSED2 && bzn) ? scale2 : scale1;
  const int tid = threadIdx.x;
  const int lane = tid & 63, wave = tid >> 6;
  const int wr = wave >> 1, wc = wave & 1;
  const int m0 = byn * 128, n0 = bxn * BN;
  const int frow = lane & 15, fc = lane >> 4;

  f32x4 acc[4][NREP];
#pragma unroll
  for (int i = 0; i < 4; i++)
#pragma unroll
    for (int j = 0; j < NREP; j++)
#pragma unroll
      for (int r = 0; r < 4; r++) acc[i][j][r] = 0.f;

  const int r0 = tid >> 2, c0 = (tid & 3) ^ swz4(r0);
  const int p1 = tid + 256;
  const int r1 = p1 >> 2, c1 = (p1 & 3) ^ swz4(r1);

  const unsigned short* Ab = A + (size_t)m0 * K;
  const unsigned short* Bb = Bm + (size_t)n0 * K;

  for (int k0 = 0; k0 < K; k0 += 64) {
    __syncthreads();
#pragma unroll
    for (int hh = 0; hh < 2; hh++) {
      const int kk = k0 + hh * 32;
      gl_lds16(Ab + (size_t)r0 * K + kk + c0 * 8, &As[hh][tid * 8]);
      gl_lds16(Ab + (size_t)r1 * K + kk + c1 * 8, &As[hh][p1 * 8]);
      gl_lds16(Bb + (size_t)r0 * K + kk + c0 * 8, &Bs[hh][tid * 8]);
      if constexpr (NREP == 4)
        gl_lds16(Bb + (size_t)r1 * K + kk + c1 * 8, &Bs[hh][p1 * 8]);
    }
    __syncthreads();
#pragma unroll
    for (int hh = 0; hh < 2; hh++) {
      bf16x8 af[4], bfr[NREP];
#pragma unroll
      for (int mi = 0; mi < 4; mi++) {
        int row = wr * 64 + mi * 16 + frow;
        af[mi] = *(const bf16x8*)(&As[hh][(row * 4 + (fc ^ swz4(row))) * 8]);
      }
#pragma unroll
      for (int ni = 0; ni < NREP; ni++) {
        int row = wc * (NREP * 16) + ni * 16 + frow;
        bfr[ni] = *(const bf16x8*)(&Bs[hh][(row * 4 + (fc ^ swz4(row))) * 8]);
      }
#pragma unroll
      for (int mi = 0; mi < 4; mi++)
#pragma unroll
        for (int ni = 0; ni < NREP; ni++)
          acc[mi][ni] = MFMA(af[mi], bfr[ni], acc[mi][ni]);
    }
  }
  // epilogue: C/D layout col=lane&15, row=(lane>>4)*4+reg
#pragma unroll
  for (int ni = 0; ni < NREP; ni++) {
    const int n = n0 + wc * (NREP * 16) + ni * 16 + frow;
    const float bs = bias[n];
#pragma unroll
    for (int mi = 0; mi < 4; mi++) {
      const int mb = m0 + wr * 64 + mi * 16 + fc * 4;
#pragma unroll
      for (int r = 0; r < 4; r++) {
        const float v = (acc[mi][ni][r] + bs) * scale;
        if (BF16OUT)
          ((unsigned short*)Cout)[(size_t)(mb + r) * N + n] = f2bf(v);
        else
          ((float*)Cout)[(size_t)(mb + r) * N + n] = v;
      }
    }
  }
}

// ---------------- flash attention v2, causal, S^T formulation ----------------
// Q is PRE-SCALED by (1/sqrt(HD))*log2(e); softmax in exp2 domain.
// 1-D grid 512, XCD-swizzled: all 16 pi-blocks of one (b,h) land on one XCD
// (bid&7 = XCD round-robin) so K/V (1MB) is fetched into that L2 once.
// Each block: paired q-tiles (31-pi, pi) -> uniform 33 k-tile units.
// T13 defer-max (round 7, +1 us): wave-uniform LOCAL-max test skips both
// shfl_xor reduces and the O-rescale in the common case.
__global__ __launch_bounds__(256, 2) void attn2_kernel(
    const unsigned short* __restrict__ Q, const unsigned short* __restrict__ Kg,
    const unsigned short* __restrict__ Vt, unsigned short* __restrict__ O) {
  __shared__ __align__(16) unsigned short sK[2][64 * 128];  // [key][hd], swizzled
  __shared__ __align__(16) unsigned short sV[2][64 * 128];  // [hd][key], swizzled
  const int tid = threadIdx.x, l = tid & 63, w = tid >> 6;
  const int g = l >> 4, q15 = l & 15;
  const int bid = blockIdx.x;
  const int xcd = bid & 7, rest = bid >> 3;
  const int gidx = xcd + 8 * (rest & 3);  // (b,h) group 0..31
  const int pi = rest >> 2;               // 0..15
  const int h = gidx & 15, b = gidx >> 4;

  for (int half = 0; half < 2; half++) {
    const int qt = half == 0 ? (31 - pi) : pi;
    const int q0 = qt * 64;
    const int nkb = qt + 1;
    const int q = q0 + w * 16 + q15;  // this lane's q column

    __syncthreads();  // buffer reuse safety across halves
    // stage tile 0 -> buf 0
    for (int i = 0; i < 4; i++) {
      const int idx = tid + i * 256;
      const int key = idx >> 4, cc = (idx & 15) ^ (key & 15);
      gl_lds16(Kg + (size_t)(b * kT + key) * kD + h * kHD + cc * 8,
               &sK[0][idx * 8]);
    }
    for (int i = 0; i < 4; i++) {
      const int idx = tid + i * 256;
      const int hd = idx >> 3;
      const int cc = (idx & 7) ^ (hd & 7) ^ (((hd >> 3) & 1) << 2);
      gl_lds16(Vt + ((size_t)((b * kH + h) * kHD + hd)) * kT + cc * 8,
               &sV[0][idx * 8]);
    }

    // Q B-frags (lane holds Q[q][hd = kk*32 + g*8 .. +7])
    bf16x8 qf[4];
    const unsigned short* Qrow = Q + (size_t)(b * kT + q) * kD + h * kHD;
#pragma unroll
    for (int kk = 0; kk < 4; kk++)
      qf[kk] = *(const bf16x8*)(Qrow + kk * 32 + g * 8);

    f32x4 oacc[8];
#pragma unroll
    for (int ni = 0; ni < 8; ni++)
      for (int r = 0; r < 4; r++) oacc[ni][r] = 0.f;
    float m_i = -1e30f, l_i = 0.f;

    for (int kb = 0; kb < nkb; kb++) {
      const int bb = kb & 1;
      __syncthreads();  // drains prefetch(kb) [compiler vmcnt], syncs buffers
      if (kb + 1 < nkb) {
        const int k0n = (kb + 1) * 64;
        const int nb = 1 - bb;
#pragma unroll
        for (int i = 0; i < 4; i++) {
          const int idx = tid + i * 256;
          const int key = idx >> 4, cc = (idx & 15) ^ (key & 15);
          gl_lds16(Kg + (size_t)(b * kT + k0n + key) * kD + h * kHD + cc * 8,
                   &sK[nb][idx * 8]);
        }
#pragma unroll
        for (int i = 0; i < 4; i++) {
          const int idx = tid + i * 256;
          const int hd = idx >> 3;
          const int cc = (idx & 7) ^ (hd & 7) ^ (((hd >> 3) & 1) << 2);
          gl_lds16(Vt + ((size_t)((b * kH + h) * kHD + hd)) * kT + k0n + cc * 8,
                   &sV[nb][idx * 8]);
        }
      }

      // S^T = K Q^T : lane holds S^T[key = s*16 + g*4 + r][q]
      f32x4 st[4];
#pragma unroll
      for (int s = 0; s < 4; s++)
        for (int r = 0; r < 4; r++) st[s][r] = 0.f;
#pragma unroll
      for (int s = 0; s < 4; s++) {
        const int key = s * 16 + q15;  // A-frag row for this lane
#pragma unroll
        for (int kk = 0; kk < 4; kk++) {
          bf16x8 kf = *(const bf16x8*)(
              &sK[bb][(key * 16 + ((kk * 4 + g) ^ (key & 15))) * 8]);
          st[s] = MFMA(kf, qf[kk], st[s]);
        }
      }
      // causal mask (diagonal tile only)
      if (kb == nkb - 1) {
        const int k0 = kb * 64;
#pragma unroll
        for (int s = 0; s < 4; s++)
          for (int r = 0; r < 4; r++)
            if (k0 + s * 16 + g * 4 + r > q) st[s][r] = -1e30f;
      }
      // online softmax (exp2 domain; Q pre-scaled). Per-lane row stats.
      float mx = -1e30f;
#pragma unroll
      for (int s = 0; s < 4; s++)
        for (int r = 0; r < 4; r++) mx = fmaxf(mx, st[s][r]);
      // T13 defer-max on LOCAL max: wave-uniform branch, common case skips
      // the two serial shfl_xor reduces and the O-rescale entirely.
      const bool defer = __all(mx - m_i <= 8.0f);
      float mn, alpha;
      if (defer) {
        mn = m_i;
        alpha = 1.f;
      } else {
        mx = fmaxf(mx, __shfl_xor(mx, 16, 64));
        mx = fmaxf(mx, __shfl_xor(mx, 32, 64));
        mn = fmaxf(m_i, mx);
        alpha = fast_exp2(m_i - mn);
      }
      float rs = 0.f;
      union { bf16x8 v; unsigned short u[8]; } pkv[2];
#pragma unroll
      for (int s = 0; s < 4; s++)
        for (int r = 0; r < 4; r++) {
          const float p = fast_exp2(st[s][r] - mn);
          rs += p;
          pkv[s >> 1].u[(s & 1) * 4 + r] = f2bf(p);  // slot j=(s&1)*4+r
        }
      rs += __shfl_xor(rs, 16, 64);
      rs += __shfl_xor(rs, 32, 64);
      m_i = mn;
      l_i = l_i * alpha + rs;
      if (!defer) {
#pragma unroll
        for (int ni = 0; ni < 8; ni++)
          for (int r = 0; r < 4; r++) oacc[ni][r] *= alpha;
      }
      // O^T += V^T P^T with K=32 MFMA; A-frag slot (g,j) = key 32c+(j>>2)*16+4g+(j&3)
#pragma unroll
      for (int ni = 0; ni < 8; ni++) {
        const int hd = ni * 16 + q15;
        const int hx = (hd & 7) ^ (((hd >> 3) & 1) << 2), base = hd * 8;
#pragma unroll
        for (int c = 0; c < 2; c++) {
          const int c4l = 8 * c + g;       // keys 32c+4g+0..3   (j=0..3)
          const int c4h = 8 * c + 4 + g;   // keys 32c+16+4g+0..3 (j=4..7)
          bf16x4 lo = *(const bf16x4*)(
              &sV[bb][(base + ((c4l >> 1) ^ hx)) * 8 + (c4l & 1) * 4]);
          bf16x4 hi = *(const bf16x4*)(
              &sV[bb][(base + ((c4h >> 1) ^ hx)) * 8 + (c4h & 1) * 4]);
          bf16x8 vf = __builtin_shufflevector(lo, hi, 0, 1, 2, 3, 4, 5, 6, 7);
          oacc[ni] = MFMA(vf, pkv[c].v, oacc[ni]);
        }
      }
    }
    // epilogue: O^T C-layout -> O[b][t=q][h*128 + hd], 4 contiguous d per lane
    const float inv = 1.f / l_i;
    unsigned short* Orow = O + (size_t)(b * kT + q) * kD + h * kHD;
#pragma unroll
    for (int ni = 0; ni < 8; ni++) {
      ushort4 o4;
      o4.x = f2bf(oacc[ni][0] * inv);
      o4.y = f2bf(oacc[ni][1] * inv);
      o4.z = f2bf(oacc[ni][2] * inv);
      o4.w = f2bf(oacc[ni][3] * inv);
      *(ushort4*)(Orow + ni * 16 + g * 4) = o4;
    }
  }
}

extern "C" void kernel_launch(void* const* d_in, const int* in_sizes, int n_in,
                              void* d_out, int out_size, void* d_ws, size_t ws_size,
                              hipStream_t stream) {
  const float* x       = (const float*)d_in[0];
  const float* Wq      = (const float*)d_in[1];
  const float* bq      = (const float*)d_in[2];
  const float* Wk      = (const float*)d_in[3];
  const float* bk      = (const float*)d_in[4];
  // d_in[5] Wvq, d_in[6] bvq, d_in[7] v_keys: dead (top_k selects all NVK)
  const float* v_embed = (const float*)d_in[8];
  const float* Wo      = (const float*)d_in[9];
  const float* bo      = (const float*)d_in[10];
  float* out = (float*)d_out;

  char* w = (char*)d_ws;
  unsigned short* xb  = (unsigned short*)w; w += (size_t)kBT * kD * 2;  // 16MB
  unsigned short* qb  = (unsigned short*)w; w += (size_t)kBT * kD * 2;
  unsigned short* kb  = (unsigned short*)w; w += (size_t)kBT * kD * 2;
  unsigned short* ob  = (unsigned short*)w; w += (size_t)kBT * kD * 2;
  unsigned short* vtb = (unsigned short*)w; w += (size_t)kBT * kD * 2;
  unsigned short* wqb = (unsigned short*)w; w += (size_t)kD * kD * 2;   // 8MB
  unsigned short* wkb = (unsigned short*)w; w += (size_t)kD * kD * 2;
  unsigned short* wob = (unsigned short*)w; w += (size_t)kD * kD * 2;

  // fused prep: make_vt (+x->bf16 reuse of the x read) + 3 weight converts
  prep_kernel<<<dim3(1024 + 3 * 4096), 256, 0, stream>>>(
      x, v_embed, Wq, Wk, Wo, vtb, xb, wqb, wkb, wob);

  // fold softmax scale (1/sqrt(HD) * log2(e), exp2 domain) into Q projection
  const float scaleQ = 0.08838834764831845f * 1.4426950408889634f;
  // fused Q+K projections: 256x256-tile 8-phase pipeline, 256 blocks = 1/CU
  gemm8p_qk<<<dim3(kD / 256, kBT / 256, 2), 512, 0, stream>>>(
      xb, wqb, wkb, bq, bk, qb, kb, scaleQ, 1.0f);

  attn2_kernel<<<dim3(512), 256, 0, stream>>>(qb, kb, vtb, ob);

  // out-projection: 128x128 @ 512 blocks (best-known; small-tile variants lost)
  gemm_bt<4, false, false><<<dim3(kD / 128, kBT / 128, 1), 256, 0, stream>>>(
      ob, wob, nullptr, bo, nullptr, out, nullptr, 1.0f, 1.0f);
}